// Round 1
// baseline (349.243 us; speedup 1.0000x reference)
//
#include <hip/hip_runtime.h>

// ContentBasedAttention: y = softmax(cos_sim(x1@WQ, x2@WK)) @ (x2@WV)
// B=4, S=2048, D=1024. All-fp32 in/out; internal compute bf16 MFMA.

typedef __attribute__((ext_vector_type(4))) float f32x4;
typedef __attribute__((ext_vector_type(4))) unsigned short u16x4;
typedef __attribute__((ext_vector_type(8))) unsigned short u16x8;
typedef __attribute__((ext_vector_type(8))) __bf16 bf16x8;

__device__ __forceinline__ unsigned short f2b(float f) {
  // RNE float->bf16 (inputs are finite randoms; no NaN handling needed)
  unsigned u = __float_as_uint(f);
  u += 0x7FFFu + ((u >> 16) & 1u);
  return (unsigned short)(u >> 16);
}
__device__ __forceinline__ float b2f(unsigned short h) {
  return __uint_as_float(((unsigned)h) << 16);
}

__device__ __forceinline__ void gl_lds16(const void* g, void* l) {
  __builtin_amdgcn_global_load_lds(
      (const __attribute__((address_space(1))) void*)g,
      (__attribute__((address_space(3))) void*)l, 16, 0, 0);
}

// ---------------- elementwise converts ----------------

__global__ void cvt_f32_bf16(const float* __restrict__ in, unsigned short* __restrict__ out) {
  long long i = (long long)(blockIdx.x * 256 + threadIdx.x) * 8;
  f32x4 a = *(const f32x4*)(in + i);
  f32x4 b = *(const f32x4*)(in + i + 4);
  u16x8 o;
  o[0] = f2b(a[0]); o[1] = f2b(a[1]); o[2] = f2b(a[2]); o[3] = f2b(a[3]);
  o[4] = f2b(b[0]); o[5] = f2b(b[1]); o[6] = f2b(b[2]); o[7] = f2b(b[3]);
  *(u16x8*)(out + i) = o;
}

// fp32 [1024,1024] -> transposed bf16 [1024,1024] (out[e,d] = in[d,e]), 3 mats via z
__global__ void cvt_w_T(const float* __restrict__ w0, const float* __restrict__ w1,
                        const float* __restrict__ w2,
                        unsigned short* __restrict__ o0, unsigned short* __restrict__ o1,
                        unsigned short* __restrict__ o2) {
  const float* src = blockIdx.z == 0 ? w0 : (blockIdx.z == 1 ? w1 : w2);
  unsigned short* dst = blockIdx.z == 0 ? o0 : (blockIdx.z == 1 ? o1 : o2);
  __shared__ float tile[32][33];
  const int t = threadIdx.x;
  const int r = t >> 3, c4 = (t & 7) << 2;
  f32x4 v = *(const f32x4*)(src + (long long)(blockIdx.y * 32 + r) * 1024 + blockIdx.x * 32 + c4);
  tile[r][c4 + 0] = v[0]; tile[r][c4 + 1] = v[1];
  tile[r][c4 + 2] = v[2]; tile[r][c4 + 3] = v[3];
  __syncthreads();
  u16x4 ov;
  ov[0] = f2b(tile[c4 + 0][r]); ov[1] = f2b(tile[c4 + 1][r]);
  ov[2] = f2b(tile[c4 + 2][r]); ov[3] = f2b(tile[c4 + 3][r]);
  *(u16x4*)(dst + (long long)(blockIdx.x * 32 + r) * 1024 + blockIdx.y * 32 + c4) = ov;
}

// ---------------- per-row rsqrt(sum of squares) for q and k ----------------

__global__ void rownorm(const unsigned short* __restrict__ qb, const unsigned short* __restrict__ kb,
                        float* __restrict__ rq, float* __restrict__ rk) {
  const int row = blockIdx.x;  // 0..16383: first 8192 = q rows, rest = k rows
  const unsigned short* src;
  float* dst;
  if (row < 8192) { src = qb + (long long)row * 1024; dst = rq + row; }
  else            { src = kb + (long long)(row - 8192) * 1024; dst = rk + (row - 8192); }
  const int t = threadIdx.x;  // 256 threads, 4 bf16 each
  u16x4 v = *(const u16x4*)(src + t * 4);
  float s = 0.f;
#pragma unroll
  for (int i = 0; i < 4; ++i) { float f = b2f(v[i]); s += f * f; }
#pragma unroll
  for (int o = 32; o; o >>= 1) s += __shfl_xor(s, o);
  __shared__ float red[4];
  if ((t & 63) == 0) red[t >> 6] = s;
  __syncthreads();
  if (t == 0) {
    float tot = red[0] + red[1] + red[2] + red[3];
    *dst = rsqrtf(fmaxf(tot, 1e-12f));
  }
}

// ---------------- in-place row softmax over bf16 scores [*, 2048] ----------------

__global__ void softmax_rows(unsigned short* __restrict__ zb) {
  unsigned short* zr = zb + (long long)blockIdx.x * 2048;
  const int t = threadIdx.x;  // 256 threads x 8 elems
  u16x8 v = *(const u16x8*)(zr + t * 8);
  float f[8];
#pragma unroll
  for (int i = 0; i < 8; ++i) f[i] = b2f(v[i]);
  float mx = f[0];
#pragma unroll
  for (int i = 1; i < 8; ++i) mx = fmaxf(mx, f[i]);
#pragma unroll
  for (int o = 32; o; o >>= 1) mx = fmaxf(mx, __shfl_xor(mx, o));
  __shared__ float red[4];
  if ((t & 63) == 0) red[t >> 6] = mx;
  __syncthreads();
  mx = fmaxf(fmaxf(red[0], red[1]), fmaxf(red[2], red[3]));
  float s = 0.f;
#pragma unroll
  for (int i = 0; i < 8; ++i) { f[i] = __expf(f[i] - mx); s += f[i]; }
  __syncthreads();  // protect red[] reuse
#pragma unroll
  for (int o = 32; o; o >>= 1) s += __shfl_xor(s, o);
  if ((t & 63) == 0) red[t >> 6] = s;
  __syncthreads();
  s = red[0] + red[1] + red[2] + red[3];
  float inv = 1.0f / s;
  u16x8 o8;
#pragma unroll
  for (int i = 0; i < 8; ++i) o8[i] = f2b(f[i] * inv);
  *(u16x8*)(zr + t * 8) = o8;  // each thread rewrites only its own 16B slot
}

// ---------------- GEMM_BT: C[m,n] = sum_k A[m,k]*B[n,k] (both [*,K] row-major bf16) ----------
// m97 structure: 128x128 tile, BK=32, 4 waves (2x2 of 64x64), 16x16x32 bf16 MFMA,
// global_load_lds width-16 staging, 2 barriers per K-step.
// MODE 0: store bf16. MODE 1: store bf16 of acc*rowS[m]*colS[n] (cosine scores).
// MODE 2: store fp32.

template <int MODE>
__global__ __launch_bounds__(256) void gemm_bt(
    const unsigned short* __restrict__ A, const unsigned short* __restrict__ B,
    void* __restrict__ C, int K, int lda, int ldb, int ldc,
    long long strideA, long long strideB, long long strideC,
    const float* __restrict__ rowS, const float* __restrict__ colS, int scaleStride) {
  const int bz = blockIdx.z;
  A += (long long)bz * strideA;
  B += (long long)bz * strideB;
  const int bm0 = blockIdx.y << 7, bn0 = blockIdx.x << 7;
  __shared__ __align__(16) unsigned short smA[128 * 32];
  __shared__ __align__(16) unsigned short smB[128 * 32];
  const int t = threadIdx.x, lane = t & 63, w = t >> 6;
  const int wr = w >> 1, wc = w & 1;
  f32x4 acc[4][4] = {};

  // staging: thread t -> 8 contiguous bf16 (16B); LDS layout is linear [128][32]
  const int sr = t >> 2, sc = (t & 3) << 3;
  const unsigned short* gA0 = A + (long long)(bm0 + sr) * lda + sc;
  const unsigned short* gA1 = gA0 + (long long)64 * lda;
  const unsigned short* gB0 = B + (long long)(bn0 + sr) * ldb + sc;
  const unsigned short* gB1 = gB0 + (long long)64 * ldb;
  unsigned short* lA0 = smA + t * 8;
  unsigned short* lA1 = lA0 + 2048;
  unsigned short* lB0 = smB + t * 8;
  unsigned short* lB1 = lB0 + 2048;

  const int fr = lane & 15, fq = lane >> 4;
  const int aoff = (wr * 64 + fr) * 32 + fq * 8;
  const int boff = (wc * 64 + fr) * 32 + fq * 8;

  for (int kt = 0; kt < K; kt += 32) {
    gl_lds16(gA0, lA0); gl_lds16(gA1, lA1);
    gl_lds16(gB0, lB0); gl_lds16(gB1, lB1);
    gA0 += 32; gA1 += 32; gB0 += 32; gB1 += 32;
    __syncthreads();
    bf16x8 fa[4], fb[4];
#pragma unroll
    for (int m = 0; m < 4; ++m) fa[m] = *(const bf16x8*)(smA + aoff + m * 16 * 32);
#pragma unroll
    for (int n = 0; n < 4; ++n) fb[n] = *(const bf16x8*)(smB + boff + n * 16 * 32);
#pragma unroll
    for (int m = 0; m < 4; ++m)
#pragma unroll
      for (int n = 0; n < 4; ++n)
        acc[m][n] = __builtin_amdgcn_mfma_f32_16x16x32_bf16(fa[m], fb[n], acc[m][n], 0, 0, 0);
    __syncthreads();
  }

  // C/D frag layout (m89-verified): col = lane&15, row = (lane>>4)*4 + j
  const int r0 = bm0 + wr * 64 + fq * 4;
  const int c0 = bn0 + wc * 64 + fr;
  if constexpr (MODE == 0) {
    unsigned short* Cp = (unsigned short*)C + (long long)bz * strideC;
#pragma unroll
    for (int m = 0; m < 4; ++m)
#pragma unroll
      for (int j = 0; j < 4; ++j) {
        long long rb = (long long)(r0 + m * 16 + j) * ldc + c0;
#pragma unroll
        for (int n = 0; n < 4; ++n) Cp[rb + n * 16] = f2b(acc[m][n][j]);
      }
  } else if constexpr (MODE == 1) {
    unsigned short* Cp = (unsigned short*)C + (long long)bz * strideC;
    const float* rs = rowS + bz * scaleStride;
    const float* cs = colS + bz * scaleStride;
    float csv[4];
#pragma unroll
    for (int n = 0; n < 4; ++n) csv[n] = cs[c0 - bm0 * 0 + n * 16 - bn0 + bn0] ;  // = cs[c0 + n*16]
#pragma unroll
    for (int n = 0; n < 4; ++n) csv[n] = cs[c0 + n * 16];
#pragma unroll
    for (int m = 0; m < 4; ++m)
#pragma unroll
      for (int j = 0; j < 4; ++j) {
        float rsv = rs[r0 + m * 16 + j];
        long long rb = (long long)(r0 + m * 16 + j) * ldc + c0;
#pragma unroll
        for (int n = 0; n < 4; ++n) Cp[rb + n * 16] = f2b(acc[m][n][j] * rsv * csv[n]);
      }
  } else {
    float* Cp = (float*)C + (long long)bz * strideC;
#pragma unroll
    for (int m = 0; m < 4; ++m)
#pragma unroll
      for (int j = 0; j < 4; ++j) {
        long long rb = (long long)(r0 + m * 16 + j) * ldc + c0;
#pragma unroll
        for (int n = 0; n < 4; ++n) Cp[rb + n * 16] = acc[m][n][j];
      }
  }
}

// ---------------- launch ----------------

extern "C" void kernel_launch(void* const* d_in, const int* in_sizes, int n_in,
                              void* d_out, int out_size, void* d_ws, size_t ws_size,
                              hipStream_t stream) {
  (void)in_sizes; (void)n_in; (void)out_size; (void)ws_size;
  const float* x1 = (const float*)d_in[0];
  const float* x2 = (const float*)d_in[1];
  const float* WQ = (const float*)d_in[2];
  const float* WK = (const float*)d_in[3];
  const float* WV = (const float*)d_in[4];
  float* out = (float*)d_out;
  char* ws = (char*)d_ws;

  // workspace layout (total ~86 MB):
  //   qb, kb          bf16 [8192,1024]  (unnormalized projections)
  //   vT              bf16 [1024,8192]  (v transposed, batches side by side)
  //   rq, rk          f32  [8192]       (per-row rsqrt norms)
  //   scratch: phase A = {x1b, x2b, wqT, wkT, wvT}; phase B (reuse) = z/w bf16 [4][2048][2048]
  const long long MB16 = 16777216LL;
  unsigned short* qb = (unsigned short*)(ws);
  unsigned short* kb = (unsigned short*)(ws + MB16);
  unsigned short* vT = (unsigned short*)(ws + 2 * MB16);
  float* rq = (float*)(ws + 3 * MB16);
  float* rk = (float*)(ws + 3 * MB16 + 32768);
  char* scr = ws + 3 * MB16 + 65536;
  unsigned short* x1b = (unsigned short*)(scr);
  unsigned short* x2b = (unsigned short*)(scr + MB16);
  unsigned short* wqT = (unsigned short*)(scr + 2 * MB16);
  unsigned short* wkT = (unsigned short*)(scr + 2 * MB16 + 2097152);
  unsigned short* wvT = (unsigned short*)(scr + 2 * MB16 + 2 * 2097152);
  unsigned short* zb  = (unsigned short*)(scr);  // reused after projections

  // 1) convert inputs to bf16 (W transposed for BT-GEMM)
  cvt_f32_bf16<<<4096, 256, 0, stream>>>(x1, x1b);
  cvt_f32_bf16<<<4096, 256, 0, stream>>>(x2, x2b);
  cvt_w_T<<<dim3(32, 32, 3), 256, 0, stream>>>(WQ, WK, WV, wqT, wkT, wvT);

  // 2) projections: q = x1@WQ, k = x2@WK (bf16 out); vT = WV^T (x)GEMM_BT x2 -> v transposed
  gemm_bt<0><<<dim3(8, 64, 1), 256, 0, stream>>>(x1b, wqT, qb, 1024, 1024, 1024, 1024,
                                                 0, 0, 0, nullptr, nullptr, 0);
  gemm_bt<0><<<dim3(8, 64, 1), 256, 0, stream>>>(x2b, wkT, kb, 1024, 1024, 1024, 1024,
                                                 0, 0, 0, nullptr, nullptr, 0);
  gemm_bt<0><<<dim3(64, 8, 1), 256, 0, stream>>>(wvT, x2b, vT, 1024, 1024, 1024, 8192,
                                                 0, 0, 0, nullptr, nullptr, 0);

  // 3) per-row inverse norms of q, k
  rownorm<<<16384, 256, 0, stream>>>(qb, kb, rq, rk);

  // 4) cosine scores z[b] = (q k^T) * rq x rk, bf16, batched via grid.z
  gemm_bt<1><<<dim3(16, 16, 4), 256, 0, stream>>>(qb, kb, zb, 1024, 1024, 1024, 2048,
                                                  2048LL * 1024, 2048LL * 1024, 2048LL * 2048,
                                                  rq, rk, 2048);

  // 5) in-place row softmax (4*2048 rows of 2048)
  softmax_rows<<<8192, 256, 0, stream>>>(zb);

  // 6) y[b] = w[b] @ v[b] = GEMM_BT(w, vT_b), fp32 out
  gemm_bt<2><<<dim3(8, 16, 4), 256, 0, stream>>>(zb, vT, out, 2048, 2048, 8192, 1024,
                                                 2048LL * 2048, 2048, 2048LL * 1024,
                                                 nullptr, nullptr, 0);
}

// Round 2
// 333.493 us; speedup vs baseline: 1.0472x; 1.0472x over previous
//
#include <hip/hip_runtime.h>

// ContentBasedAttention: y = softmax(cos_sim(x1@WQ, x2@WK)) @ (x2@WV)
// B=4, S=2048, D=1024. fp32 in/out; internal bf16 MFMA, 256^2 8-phase GEMM.

typedef __attribute__((ext_vector_type(4))) float f32x4;
typedef __attribute__((ext_vector_type(4))) unsigned short u16x4;
typedef __attribute__((ext_vector_type(8))) unsigned short u16x8;
typedef __attribute__((ext_vector_type(8))) __bf16 bf16x8;

__device__ __forceinline__ unsigned short f2b(float f) {
  unsigned u = __float_as_uint(f);
  u += 0x7FFFu + ((u >> 16) & 1u);
  return (unsigned short)(u >> 16);
}
__device__ __forceinline__ float b2f(unsigned short h) {
  return __uint_as_float(((unsigned)h) << 16);
}

__device__ __forceinline__ void gl_lds16(const void* g, void* l) {
  __builtin_amdgcn_global_load_lds(
      (const __attribute__((address_space(1))) void*)g,
      (__attribute__((address_space(3))) void*)l, 16, 0, 0);
}

// ---------------- elementwise converts ----------------

__global__ void cvt_f32_bf16(const float* __restrict__ in, unsigned short* __restrict__ out) {
  long long i = (long long)(blockIdx.x * 256 + threadIdx.x) * 8;
  f32x4 a = *(const f32x4*)(in + i);
  f32x4 b = *(const f32x4*)(in + i + 4);
  u16x8 o;
  o[0] = f2b(a[0]); o[1] = f2b(a[1]); o[2] = f2b(a[2]); o[3] = f2b(a[3]);
  o[4] = f2b(b[0]); o[5] = f2b(b[1]); o[6] = f2b(b[2]); o[7] = f2b(b[3]);
  *(u16x8*)(out + i) = o;
}

__global__ void cvt_w_T(const float* __restrict__ w0, const float* __restrict__ w1,
                        const float* __restrict__ w2,
                        unsigned short* __restrict__ o0, unsigned short* __restrict__ o1,
                        unsigned short* __restrict__ o2) {
  const float* src = blockIdx.z == 0 ? w0 : (blockIdx.z == 1 ? w1 : w2);
  unsigned short* dst = blockIdx.z == 0 ? o0 : (blockIdx.z == 1 ? o1 : o2);
  __shared__ float tile[32][33];
  const int t = threadIdx.x;
  const int r = t >> 3, c4 = (t & 7) << 2;
  f32x4 v = *(const f32x4*)(src + (long long)(blockIdx.y * 32 + r) * 1024 + blockIdx.x * 32 + c4);
  tile[r][c4 + 0] = v[0]; tile[r][c4 + 1] = v[1];
  tile[r][c4 + 2] = v[2]; tile[r][c4 + 3] = v[3];
  __syncthreads();
  u16x4 ov;
  ov[0] = f2b(tile[c4 + 0][r]); ov[1] = f2b(tile[c4 + 1][r]);
  ov[2] = f2b(tile[c4 + 2][r]); ov[3] = f2b(tile[c4 + 3][r]);
  *(u16x4*)(dst + (long long)(blockIdx.x * 32 + r) * 1024 + blockIdx.y * 32 + c4) = ov;
}

// ---------------- per-row rsqrt(sum sq) ----------------

__global__ void rownorm(const unsigned short* __restrict__ qb, const unsigned short* __restrict__ kb,
                        float* __restrict__ rq, float* __restrict__ rk) {
  const int row = blockIdx.x;
  const unsigned short* src;
  float* dst;
  if (row < 8192) { src = qb + (long long)row * 1024; dst = rq + row; }
  else            { src = kb + (long long)(row - 8192) * 1024; dst = rk + (row - 8192); }
  const int t = threadIdx.x;
  u16x4 v = *(const u16x4*)(src + t * 4);
  float s = 0.f;
#pragma unroll
  for (int i = 0; i < 4; ++i) { float f = b2f(v[i]); s += f * f; }
#pragma unroll
  for (int o = 32; o; o >>= 1) s += __shfl_xor(s, o);
  __shared__ float red[4];
  if ((t & 63) == 0) red[t >> 6] = s;
  __syncthreads();
  if (t == 0) {
    float tot = red[0] + red[1] + red[2] + red[3];
    *dst = rsqrtf(fmaxf(tot, 1e-12f));
  }
}

// ---------------- in-place row softmax over bf16 [*, 2048] ----------------

__global__ void softmax_rows(unsigned short* __restrict__ zb) {
  unsigned short* zr = zb + (long long)blockIdx.x * 2048;
  const int t = threadIdx.x;
  u16x8 v = *(const u16x8*)(zr + t * 8);
  float f[8];
#pragma unroll
  for (int i = 0; i < 8; ++i) f[i] = b2f(v[i]);
  float mx = f[0];
#pragma unroll
  for (int i = 1; i < 8; ++i) mx = fmaxf(mx, f[i]);
#pragma unroll
  for (int o = 32; o; o >>= 1) mx = fmaxf(mx, __shfl_xor(mx, o));
  __shared__ float red[4];
  if ((t & 63) == 0) red[t >> 6] = mx;
  __syncthreads();
  mx = fmaxf(fmaxf(red[0], red[1]), fmaxf(red[2], red[3]));
  float s = 0.f;
#pragma unroll
  for (int i = 0; i < 8; ++i) { f[i] = __expf(f[i] - mx); s += f[i]; }
  __syncthreads();
#pragma unroll
  for (int o = 32; o; o >>= 1) s += __shfl_xor(s, o);
  if ((t & 63) == 0) red[t >> 6] = s;
  __syncthreads();
  s = red[0] + red[1] + red[2] + red[3];
  float inv = 1.0f / s;
  u16x8 o8;
#pragma unroll
  for (int i = 0; i < 8; ++i) o8[i] = f2b(f[i] * inv);
  *(u16x8*)(zr + t * 8) = o8;
}

// ---------------- 256x256 8-phase GEMM_BT ----------------
// C[m,n] = sum_k A[m,k]*B[n,k], A/B row-major bf16 [rows, K].
// BM=BN=256, BK=64, 8 waves (2M x 4N), 512 threads, 128 KiB LDS.
// Regions (staging granularity) = K-halves: per K-tile {Ak0, Bk0, Ak1, Bk1},
// each 256 rows x 32 K = 16 KB = 2 global_load_lds dwordx4 per thread.
// Schedule: 4 sub-phases per K-tile q=(ks,mh); stage region j = phase+6;
// counted vmcnt(8) at q=1/q=3 (tail: 4 -> 0). T2 swizzle: LDS byte ^= (row&3)<<4,
// applied via pre-swizzled GLOBAL source col + swizzled ds_read (rule 21).
// MODE 0: bf16 C.  MODE 1: bf16 of acc*rowS[m]*colS[n].  MODE 2: fp32 C.
// B operand = (bm0 < bSplit ? B0 : B1) — lets one launch do q (WQ) and k (WK).

template <int MODE>
__global__ __launch_bounds__(512, 2) void gemm256(
    const unsigned short* __restrict__ A,
    const unsigned short* __restrict__ B0, const unsigned short* __restrict__ B1, int bSplit,
    void* __restrict__ C, int K, int lda, int ldb, int ldc,
    long long strideA, long long strideB, long long strideC,
    const float* __restrict__ rowS, const float* __restrict__ colS, int scaleStride) {
  __shared__ __align__(16) unsigned short sA[2][2][256 * 32];
  __shared__ __align__(16) unsigned short sB[2][2][256 * 32];
  const int bz = blockIdx.z;
  const int bm0 = blockIdx.y << 8, bn0 = blockIdx.x << 8;
  const unsigned short* Ab = A + (long long)bz * strideA;
  const unsigned short* Bb = ((bm0 < bSplit) ? B0 : B1) + (long long)bz * strideB;

  const int t = threadIdx.x, l = t & 63, w = t >> 6;
  const int wr = w >> 2, wc = w & 3;           // wave tile: 128 rows x 64 cols
  const int fr = l & 15, fq = l >> 4;

  // staging source (pre-swizzled global col so linear LDS dest == swizzled layout)
  const int srow = 16 * w + (l >> 2);
  const int scol = ((l & 3) * 8) ^ (((l >> 2) & 3) * 8);
  const long long ldaL = lda, ldbL = ldb;
  const unsigned short* gA = Ab + (long long)(bm0 + srow) * ldaL + scol;
  const unsigned short* gB = Bb + (long long)(bn0 + srow) * ldbL + scol;

  f32x4 acc[8][4] = {};
  const int NKT = K >> 6;

  auto STAGE = [&](int j) {
    const int ktw = j >> 2, r = j & 3, p = ktw & 1, h = (r >> 1) & 1;
    const long long kc = (long long)(ktw << 6) + (h << 5);
    if ((r & 1) == 0) {
      unsigned short* d = &sA[p][h][w * 512];
      gl_lds16(gA + kc, d);
      gl_lds16(gA + kc + 128 * ldaL, d + 4096);
    } else {
      unsigned short* d = &sB[p][h][w * 512];
      gl_lds16(gB + kc, d);
      gl_lds16(gB + kc + 128 * ldbL, d + 4096);
    }
  };

  // swizzled ds_read element offset within a [256][32] region
  const int swz = (fq * 8) ^ ((fr & 3) * 8);

  // prologue: stage regions 0..5 (kt0 fully + kt1 K-half0); need 0,1 landed -> vmcnt(8)
#pragma unroll
  for (int j = 0; j < 6; ++j) STAGE(j);
  asm volatile("s_waitcnt vmcnt(8)" ::: "memory");
  __builtin_amdgcn_s_barrier();

  for (int kt = 0; kt < NKT; ++kt) {
    const int p = kt & 1;
    const bool last = (kt == NKT - 1), pen = (kt == NKT - 2);
    const unsigned short* a0 = &sA[p][0][0];
    const unsigned short* a1 = &sA[p][1][0];
    const unsigned short* b0p = &sB[p][0][0];
    const unsigned short* b1p = &sB[p][1][0];
    const int jb = 4 * kt, jmax = 4 * NKT;
    bf16x8 bf[4], af[4];

    // ---- q=0: ks=0, mh=0
#pragma unroll
    for (int n = 0; n < 4; ++n)
      bf[n] = *(const bf16x8*)(b0p + (wc * 64 + n * 16 + fr) * 32 + swz);
#pragma unroll
    for (int m = 0; m < 4; ++m)
      af[m] = *(const bf16x8*)(a0 + (wr * 128 + m * 16 + fr) * 32 + swz);
    if (jb + 6 < jmax) STAGE(jb + 6);
    __builtin_amdgcn_s_barrier();
    __builtin_amdgcn_s_setprio(1);
#pragma unroll
    for (int m = 0; m < 4; ++m)
#pragma unroll
      for (int n = 0; n < 4; ++n)
        acc[m][n] = __builtin_amdgcn_mfma_f32_16x16x32_bf16(af[m], bf[n], acc[m][n], 0, 0, 0);
    __builtin_amdgcn_s_setprio(0);
    __builtin_amdgcn_s_barrier();

    // ---- q=1: ks=0, mh=1 (reuse bf)
#pragma unroll
    for (int m = 0; m < 4; ++m)
      af[m] = *(const bf16x8*)(a0 + (wr * 128 + 64 + m * 16 + fr) * 32 + swz);
    if (jb + 7 < jmax) STAGE(jb + 7);
    if (last) asm volatile("s_waitcnt vmcnt(0)" ::: "memory");
    else      asm volatile("s_waitcnt vmcnt(8)" ::: "memory");
    __builtin_amdgcn_s_barrier();
    __builtin_amdgcn_s_setprio(1);
#pragma unroll
    for (int m = 0; m < 4; ++m)
#pragma unroll
      for (int n = 0; n < 4; ++n)
        acc[4 + m][n] = __builtin_amdgcn_mfma_f32_16x16x32_bf16(af[m], bf[n], acc[4 + m][n], 0, 0, 0);
    __builtin_amdgcn_s_setprio(0);
    __builtin_amdgcn_s_barrier();

    // ---- q=2: ks=1, mh=0
#pragma unroll
    for (int n = 0; n < 4; ++n)
      bf[n] = *(const bf16x8*)(b1p + (wc * 64 + n * 16 + fr) * 32 + swz);
#pragma unroll
    for (int m = 0; m < 4; ++m)
      af[m] = *(const bf16x8*)(a1 + (wr * 128 + m * 16 + fr) * 32 + swz);
    if (jb + 8 < jmax) STAGE(jb + 8);
    __builtin_amdgcn_s_barrier();
    __builtin_amdgcn_s_setprio(1);
#pragma unroll
    for (int m = 0; m < 4; ++m)
#pragma unroll
      for (int n = 0; n < 4; ++n)
        acc[m][n] = __builtin_amdgcn_mfma_f32_16x16x32_bf16(af[m], bf[n], acc[m][n], 0, 0, 0);
    __builtin_amdgcn_s_setprio(0);
    __builtin_amdgcn_s_barrier();

    // ---- q=3: ks=1, mh=1 (reuse bf)
#pragma unroll
    for (int m = 0; m < 4; ++m)
      af[m] = *(const bf16x8*)(a1 + (wr * 128 + 64 + m * 16 + fr) * 32 + swz);
    if (jb + 9 < jmax) STAGE(jb + 9);
    if (!last) {
      if (pen) asm volatile("s_waitcnt vmcnt(4)" ::: "memory");
      else     asm volatile("s_waitcnt vmcnt(8)" ::: "memory");
    }
    __builtin_amdgcn_s_barrier();
    __builtin_amdgcn_s_setprio(1);
#pragma unroll
    for (int m = 0; m < 4; ++m)
#pragma unroll
      for (int n = 0; n < 4; ++n)
        acc[4 + m][n] = __builtin_amdgcn_mfma_f32_16x16x32_bf16(af[m], bf[n], acc[4 + m][n], 0, 0, 0);
    __builtin_amdgcn_s_setprio(0);
    __builtin_amdgcn_s_barrier();
  }

  // epilogue: acc[mh*4+mf][n][jj] -> row bm0+wr*128+mh*64+mf*16+fq*4+jj, col bn0+wc*64+n*16+fr
  const int r0 = bm0 + wr * 128 + fq * 4;
  const int c0 = bn0 + wc * 64 + fr;
  if constexpr (MODE == 0) {
    unsigned short* Cp = (unsigned short*)C + (long long)bz * strideC;
#pragma unroll
    for (int m = 0; m < 8; ++m)
#pragma unroll
      for (int jj = 0; jj < 4; ++jj) {
        const int rr = r0 + (m >> 2) * 64 + (m & 3) * 16 + jj;
        const long long rb = (long long)rr * ldc + c0;
#pragma unroll
        for (int n = 0; n < 4; ++n) Cp[rb + n * 16] = f2b(acc[m][n][jj]);
      }
  } else if constexpr (MODE == 1) {
    unsigned short* Cp = (unsigned short*)C + (long long)bz * strideC;
    const float* rs = rowS + bz * scaleStride;
    const float* cs = colS + bz * scaleStride;
    float csv[4];
#pragma unroll
    for (int n = 0; n < 4; ++n) csv[n] = cs[c0 - bm0 + bm0 + n * 16];
#pragma unroll
    for (int n = 0; n < 4; ++n) csv[n] = cs[c0 + n * 16];
#pragma unroll
    for (int m = 0; m < 8; ++m)
#pragma unroll
      for (int jj = 0; jj < 4; ++jj) {
        const int rr = r0 + (m >> 2) * 64 + (m & 3) * 16 + jj;
        const float rsv = rs[rr];
        const long long rb = (long long)rr * ldc + c0;
#pragma unroll
        for (int n = 0; n < 4; ++n) Cp[rb + n * 16] = f2b(acc[m][n][jj] * rsv * csv[n]);
      }
  } else {
    float* Cp = (float*)C + (long long)bz * strideC;
#pragma unroll
    for (int m = 0; m < 8; ++m)
#pragma unroll
      for (int jj = 0; jj < 4; ++jj) {
        const int rr = r0 + (m >> 2) * 64 + (m & 3) * 16 + jj;
        const long long rb = (long long)rr * ldc + c0;
#pragma unroll
        for (int n = 0; n < 4; ++n) Cp[rb + n * 16] = acc[m][n][jj];
      }
  }
}

// ---------------- launch ----------------

extern "C" void kernel_launch(void* const* d_in, const int* in_sizes, int n_in,
                              void* d_out, int out_size, void* d_ws, size_t ws_size,
                              hipStream_t stream) {
  (void)in_sizes; (void)n_in; (void)out_size; (void)ws_size;
  const float* x1 = (const float*)d_in[0];
  const float* x2 = (const float*)d_in[1];
  const float* WQ = (const float*)d_in[2];
  const float* WK = (const float*)d_in[3];
  const float* WV = (const float*)d_in[4];
  float* out = (float*)d_out;
  char* ws = (char*)d_ws;

  // ws layout: qb[8192,1024] || kb[8192,1024] (contiguous -> one 16384-row C),
  // vT[1024,8192], rq/rk, scratch {x1b||x2b (contiguous 16384-row A), wqT,wkT,wvT} / zb
  const long long MB16 = 16777216LL;
  unsigned short* qb = (unsigned short*)(ws);
  unsigned short* kb = (unsigned short*)(ws + MB16);
  unsigned short* vT = (unsigned short*)(ws + 2 * MB16);
  float* rq = (float*)(ws + 3 * MB16);
  float* rk = (float*)(ws + 3 * MB16 + 32768);
  char* scr = ws + 3 * MB16 + 65536;
  unsigned short* x1b = (unsigned short*)(scr);
  unsigned short* x2b = (unsigned short*)(scr + MB16);
  unsigned short* wqT = (unsigned short*)(scr + 2 * MB16);
  unsigned short* wkT = (unsigned short*)(scr + 2 * MB16 + 2097152);
  unsigned short* wvT = (unsigned short*)(scr + 2 * MB16 + 2 * 2097152);
  unsigned short* zb  = (unsigned short*)(scr);  // reused after projections

  cvt_f32_bf16<<<4096, 256, 0, stream>>>(x1, x1b);
  cvt_f32_bf16<<<4096, 256, 0, stream>>>(x2, x2b);
  cvt_w_T<<<dim3(32, 32, 3), 256, 0, stream>>>(WQ, WK, WV, wqT, wkT, wvT);

  // merged q+k projection: rows 0..8191 use WQ, 8192..16383 use WK; C = qb||kb
  gemm256<0><<<dim3(4, 64, 1), 512, 0, stream>>>(
      x1b, wqT, wkT, 8192, qb, 1024, 1024, 1024, 1024, 0, 0, 0, nullptr, nullptr, 0);

  // vT[e, n] = sum_k WV[k,e] * x2[n,k]  (v transposed, batches side by side)
  gemm256<0><<<dim3(32, 4, 1), 512, 0, stream>>>(
      wvT, x2b, x2b, 1 << 30, vT, 1024, 1024, 1024, 8192, 0, 0, 0, nullptr, nullptr, 0);

  rownorm<<<16384, 256, 0, stream>>>(qb, kb, rq, rk);

  // cosine scores z[b] = (q k^T) * rq x rk -> bf16
  gemm256<1><<<dim3(8, 8, 4), 512, 0, stream>>>(
      qb, kb, kb, 1 << 30, zb, 1024, 1024, 1024, 2048,
      2048LL * 1024, 2048LL * 1024, 2048LL * 2048, rq, rk, 2048);

  softmax_rows<<<8192, 256, 0, stream>>>(zb);

  // y[b] = w[b] @ v[b] via BT-gemm against vT, fp32 out
  gemm256<2><<<dim3(4, 8, 4), 512, 0, stream>>>(
      zb, vT, vT, 1 << 30, out, 2048, 2048, 8192, 1024,
      2048LL * 2048, 2048, 2048LL * 1024, nullptr, nullptr, 0);
}

// Round 3
// 296.819 us; speedup vs baseline: 1.1766x; 1.1236x over previous
//
#include <hip/hip_runtime.h>

// ContentBasedAttention: y = softmax(cos_sim(x1@WQ, x2@WK)) @ (x2@WV)
// B=4, S=2048, D=1024. fp32 in/out; internal bf16 MFMA.
// GEMM: 256xBN tile, BK=64, 8 waves (2Mx4N), slot-XOR LDS swizzle,
// 4-phase K-loop with counted vmcnt (race-free +1-tile lookahead).

typedef __attribute__((ext_vector_type(4))) float f32x4;
typedef __attribute__((ext_vector_type(4))) unsigned short u16x4;
typedef __attribute__((ext_vector_type(8))) unsigned short u16x8;
typedef __attribute__((ext_vector_type(8))) __bf16 bf16x8;

__device__ __forceinline__ unsigned short f2b(float f) {
  unsigned u = __float_as_uint(f);
  u += 0x7FFFu + ((u >> 16) & 1u);
  return (unsigned short)(u >> 16);
}
__device__ __forceinline__ float b2f(unsigned short h) {
  return __uint_as_float(((unsigned)h) << 16);
}

__device__ __forceinline__ void gl_lds16(const void* g, void* l) {
  __builtin_amdgcn_global_load_lds(
      (const __attribute__((address_space(1))) void*)g,
      (__attribute__((address_space(3))) void*)l, 16, 0, 0);
}

// ---------------- elementwise converts ----------------

__global__ void cvt_f32_bf16(const float* __restrict__ in, unsigned short* __restrict__ out) {
  long long i = (long long)(blockIdx.x * 256 + threadIdx.x) * 8;
  f32x4 a = *(const f32x4*)(in + i);
  f32x4 b = *(const f32x4*)(in + i + 4);
  u16x8 o;
  o[0] = f2b(a[0]); o[1] = f2b(a[1]); o[2] = f2b(a[2]); o[3] = f2b(a[3]);
  o[4] = f2b(b[0]); o[5] = f2b(b[1]); o[6] = f2b(b[2]); o[7] = f2b(b[3]);
  *(u16x8*)(out + i) = o;
}

__global__ void cvt_w_T(const float* __restrict__ w0, const float* __restrict__ w1,
                        const float* __restrict__ w2,
                        unsigned short* __restrict__ o0, unsigned short* __restrict__ o1,
                        unsigned short* __restrict__ o2) {
  const float* src = blockIdx.z == 0 ? w0 : (blockIdx.z == 1 ? w1 : w2);
  unsigned short* dst = blockIdx.z == 0 ? o0 : (blockIdx.z == 1 ? o1 : o2);
  __shared__ float tile[32][33];
  const int t = threadIdx.x;
  const int r = t >> 3, c4 = (t & 7) << 2;
  f32x4 v = *(const f32x4*)(src + (long long)(blockIdx.y * 32 + r) * 1024 + blockIdx.x * 32 + c4);
  tile[r][c4 + 0] = v[0]; tile[r][c4 + 1] = v[1];
  tile[r][c4 + 2] = v[2]; tile[r][c4 + 3] = v[3];
  __syncthreads();
  u16x4 ov;
  ov[0] = f2b(tile[c4 + 0][r]); ov[1] = f2b(tile[c4 + 1][r]);
  ov[2] = f2b(tile[c4 + 2][r]); ov[3] = f2b(tile[c4 + 3][r]);
  *(u16x4*)(dst + (long long)(blockIdx.x * 32 + r) * 1024 + blockIdx.y * 32 + c4) = ov;
}

// ---------------- per-row rsqrt(sum sq) ----------------

__global__ void rownorm(const unsigned short* __restrict__ qb, const unsigned short* __restrict__ kb,
                        float* __restrict__ rq, float* __restrict__ rk) {
  const int row = blockIdx.x;
  const unsigned short* src;
  float* dst;
  if (row < 8192) { src = qb + (long long)row * 1024; dst = rq + row; }
  else            { src = kb + (long long)(row - 8192) * 1024; dst = rk + (row - 8192); }
  const int t = threadIdx.x;
  u16x4 v = *(const u16x4*)(src + t * 4);
  float s = 0.f;
#pragma unroll
  for (int i = 0; i < 4; ++i) { float f = b2f(v[i]); s += f * f; }
#pragma unroll
  for (int o = 32; o; o >>= 1) s += __shfl_xor(s, o);
  __shared__ float red[4];
  if ((t & 63) == 0) red[t >> 6] = s;
  __syncthreads();
  if (t == 0) {
    float tot = red[0] + red[1] + red[2] + red[3];
    *dst = rsqrtf(fmaxf(tot, 1e-12f));
  }
}

// ---------------- in-place row softmax over bf16 [*, 2048] ----------------

__global__ void softmax_rows(unsigned short* __restrict__ zb) {
  unsigned short* zr = zb + (long long)blockIdx.x * 2048;
  const int t = threadIdx.x;
  u16x8 v = *(const u16x8*)(zr + t * 8);
  float f[8];
#pragma unroll
  for (int i = 0; i < 8; ++i) f[i] = b2f(v[i]);
  float mx = f[0];
#pragma unroll
  for (int i = 1; i < 8; ++i) mx = fmaxf(mx, f[i]);
#pragma unroll
  for (int o = 32; o; o >>= 1) mx = fmaxf(mx, __shfl_xor(mx, o));
  __shared__ float red[4];
  if ((t & 63) == 0) red[t >> 6] = mx;
  __syncthreads();
  mx = fmaxf(fmaxf(red[0], red[1]), fmaxf(red[2], red[3]));
  float s = 0.f;
#pragma unroll
  for (int i = 0; i < 8; ++i) { f[i] = __expf(f[i] - mx); s += f[i]; }
  __syncthreads();
#pragma unroll
  for (int o = 32; o; o >>= 1) s += __shfl_xor(s, o);
  if ((t & 63) == 0) red[t >> 6] = s;
  __syncthreads();
  s = red[0] + red[1] + red[2] + red[3];
  float inv = 1.0f / s;
  u16x8 o8;
#pragma unroll
  for (int i = 0; i < 8; ++i) o8[i] = f2b(f[i] * inv);
  *(u16x8*)(zr + t * 8) = o8;
}

// ---------------- GEMM_BT: C[m,n] = sum_k A[m,k]*B[n,k] ----------------
// BM=256, BN=NF*64, BK=64. 512 threads = 8 waves (2M x 4N), wave tile 128 x (NF*16).
// LDS regions [128 rows][64 bf16] (128B row = 8 slots of 16B), swizzle slot ^= row&7:
// fragment read (16 rows, fixed slot) -> 2 lanes/bank (free). Staged via
// global_load_lds with pre-swizzled source col (linear LDS dest), rule 21.
// K-loop: 4 phases/K-tile (2 m-frags each); stage K-tile kt+1's units
// {B0,(B1|A02),(A02|A13),(A13|-)} at q0..q3 (always opposite buffer -> race-free);
// waits: end-q1 vmcnt(4), end-q3 vmcnt(2) (counted, never 0 in steady state).
// MODE 0: bf16 C. MODE 1: bf16 of acc*rowS[m]*colS[n]. MODE 2: fp32 C.

template <int MODE, int NF>
__global__ __launch_bounds__(512, 2) void gemm8(
    const unsigned short* __restrict__ A,
    const unsigned short* __restrict__ B0_, const unsigned short* __restrict__ B1_, int bSplit,
    void* __restrict__ C, int K, int lda, int ldb, int ldc,
    long long strideA, long long strideB, long long strideC,
    const float* __restrict__ rowS, const float* __restrict__ colS, int scaleStride) {
  constexpr int HB = NF / 2;  // B half-regions (1 or 2)
  __shared__ __align__(16) unsigned short sA[2][2][128 * 64];
  __shared__ __align__(16) unsigned short sB[2][HB][128 * 64];

  // bijective XCD swizzle (nwg = 256, %8 == 0)
  const int gx = gridDim.x, gy = gridDim.y;
  int flat = blockIdx.x + gx * (blockIdx.y + gy * blockIdx.z);
  const int cpx = (gx * gy * gridDim.z) >> 3;
  flat = (flat & 7) * cpx + (flat >> 3);
  const int bx = flat % gx;
  const int rem = flat / gx;
  const int by = rem % gy;
  const int bz = rem / gy;

  const int bm0 = by << 8, bn0 = bx * (NF * 64);
  const unsigned short* Ab = A + (long long)bz * strideA;
  const unsigned short* Bb = ((bm0 < bSplit) ? B0_ : B1_) + (long long)bz * strideB;

  const int t = threadIdx.x, l = t & 63, w = t >> 6;
  const int wr = w >> 2, wc = w & 3;
  const int fr = l & 15, fq = l >> 4;
  const long long ldaL = lda, ldbL = ldb;

  // staging source: thread t covers LDS-linear 16B chunk t -> row t>>3, slot t&7;
  // source slot = (t&7) ^ ((t>>3)&7) (involution of the read swizzle)
  const int srow = t >> 3;
  const int scolB = ((t & 7) ^ ((t >> 3) & 7)) << 3;
  const unsigned short* gAt = Ab + (long long)(bm0 + srow) * ldaL + scolB;
  const unsigned short* gBt = Bb + (long long)(bn0 + srow) * ldbL + scolB;

  // stage unit A: rg=0 -> local rows 0-63 of both halves; rg=1 -> rows 64-127
  auto SA = [&](int kcol, int pb, int rg) {
    gl_lds16(gAt + (long long)(rg * 64) * ldaL + kcol, &sA[pb][0][rg * 4096] + t * 8);
    gl_lds16(gAt + (long long)(128 + rg * 64) * ldaL + kcol, &sA[pb][1][rg * 4096] + t * 8);
  };
  // stage unit B half hbb (128 rows)
  auto SB = [&](int kcol, int pb, int hbb) {
    gl_lds16(gBt + (long long)(hbb * 128) * ldbL + kcol, &sB[pb][hbb][0] + t * 8);
    gl_lds16(gBt + (long long)(hbb * 128 + 64) * ldbL + kcol, &sB[pb][hbb][4096] + t * 8);
  };
  // swizzled fragment read: region ptr, local row, slot (=ks*4+fq)
  auto rdf = [&](const unsigned short* reg, int r, int slot) {
    return *(const bf16x8*)(reg + r * 64 + (((slot ^ r) & 7) << 3));
  };

  f32x4 acc[8][NF] = {};
  bf16x8 bfr[2][NF];
  const int NKT = K >> 6;

  // prologue: stage K-tile 0; A13 (last 2 loads) may stay in flight
  SB(0, 0, 0);
  if (HB == 2) SB(0, 0, 1);
  SA(0, 0, 0);
  SA(0, 0, 1);
  asm volatile("s_waitcnt vmcnt(2)" ::: "memory");
  __builtin_amdgcn_s_barrier();

  for (int kt = 0; kt < NKT; ++kt) {
    const int p = kt & 1, pn = p ^ 1;
    const int kc = (kt + 1) << 6;
    const bool more = (kt + 1 < NKT);
    const unsigned short* aR = &sA[p][wr][0];
    const unsigned short* bR = &sB[p][(NF == 4) ? (wc >> 1) : 0][0];

#pragma unroll
    for (int ph = 0; ph < 4; ++ph) {
      // ds-loads for this phase
      if (ph == 0) {
#pragma unroll
        for (int ks = 0; ks < 2; ++ks)
#pragma unroll
          for (int n = 0; n < NF; ++n) {
            const int brow = (NF == 4) ? ((wc & 1) * 64 + n * 16 + fr) : (wc * 32 + n * 16 + fr);
            bfr[ks][n] = rdf(bR, brow, ks * 4 + fq);
          }
      }
      bf16x8 af[2][2];
#pragma unroll
      for (int mi = 0; mi < 2; ++mi)
#pragma unroll
        for (int ks = 0; ks < 2; ++ks)
          af[mi][ks] = rdf(aR, (ph * 2 + mi) * 16 + fr, ks * 4 + fq);

      // stage one unit of K-tile kt+1 (opposite buffer pn)
      if (more) {
        if (NF == 4) {
          if (ph == 0) SB(kc, pn, 0);
          else if (ph == 1) SB(kc, pn, 1);
          else if (ph == 2) SA(kc, pn, 0);
          else SA(kc, pn, 1);
        } else {
          if (ph == 0) SB(kc, pn, 0);
          else if (ph == 1) SA(kc, pn, 0);
          else if (ph == 2) SA(kc, pn, 1);
        }
      }

      __builtin_amdgcn_s_barrier();
      asm volatile("s_waitcnt lgkmcnt(0)" ::: "memory");
      __builtin_amdgcn_s_setprio(1);
#pragma unroll
      for (int mi = 0; mi < 2; ++mi)
#pragma unroll
        for (int n = 0; n < NF; ++n)
#pragma unroll
          for (int ks = 0; ks < 2; ++ks)
            acc[ph * 2 + mi][n] = __builtin_amdgcn_mfma_f32_16x16x32_bf16(
                af[mi][ks], bfr[ks][n], acc[ph * 2 + mi][n], 0, 0, 0);
      __builtin_amdgcn_s_setprio(0);

      // counted waits at phase ends
      if (ph == 1) {
        if (more) asm volatile("s_waitcnt vmcnt(4)" ::: "memory");
        else      asm volatile("s_waitcnt vmcnt(0)" ::: "memory");
      } else if (ph == 3) {
        if (more) asm volatile("s_waitcnt vmcnt(2)" ::: "memory");
      }
      __builtin_amdgcn_s_barrier();
    }
  }

  // epilogue: acc[mf][n][jj] -> row bm0 + wr*128 + mf*16 + fq*4 + jj,
  //           col bn0 + wc*(NF*16) + n*16 + fr
  const int r0 = bm0 + wr * 128 + fq * 4;
  const int c0 = bn0 + wc * (NF * 16) + fr;
  if constexpr (MODE == 0) {
    unsigned short* Cp = (unsigned short*)C + (long long)bz * strideC;
#pragma unroll
    for (int m = 0; m < 8; ++m)
#pragma unroll
      for (int jj = 0; jj < 4; ++jj) {
        const long long rb = (long long)(r0 + m * 16 + jj) * ldc + c0;
#pragma unroll
        for (int n = 0; n < NF; ++n) Cp[rb + n * 16] = f2b(acc[m][n][jj]);
      }
  } else if constexpr (MODE == 1) {
    unsigned short* Cp = (unsigned short*)C + (long long)bz * strideC;
    const float* rs = rowS + bz * scaleStride;
    const float* cs = colS + bz * scaleStride;
    float csv[NF];
#pragma unroll
    for (int n = 0; n < NF; ++n) csv[n] = cs[c0 + n * 16];
#pragma unroll
    for (int m = 0; m < 8; ++m)
#pragma unroll
      for (int jj = 0; jj < 4; ++jj) {
        const int rr = r0 + m * 16 + jj;
        const float rsv = rs[rr];
        const long long rb = (long long)rr * ldc + c0;
#pragma unroll
        for (int n = 0; n < NF; ++n) Cp[rb + n * 16] = f2b(acc[m][n][jj] * rsv * csv[n]);
      }
  } else {
    float* Cp = (float*)C + (long long)bz * strideC;
#pragma unroll
    for (int m = 0; m < 8; ++m)
#pragma unroll
      for (int jj = 0; jj < 4; ++jj) {
        const long long rb = (long long)(r0 + m * 16 + jj) * ldc + c0;
#pragma unroll
        for (int n = 0; n < NF; ++n) Cp[rb + n * 16] = acc[m][n][jj];
      }
  }
}

// ---------------- launch ----------------

extern "C" void kernel_launch(void* const* d_in, const int* in_sizes, int n_in,
                              void* d_out, int out_size, void* d_ws, size_t ws_size,
                              hipStream_t stream) {
  (void)in_sizes; (void)n_in; (void)out_size; (void)ws_size;
  const float* x1 = (const float*)d_in[0];
  const float* x2 = (const float*)d_in[1];
  const float* WQ = (const float*)d_in[2];
  const float* WK = (const float*)d_in[3];
  const float* WV = (const float*)d_in[4];
  float* out = (float*)d_out;
  char* ws = (char*)d_ws;

  const long long MB16 = 16777216LL;
  unsigned short* qb = (unsigned short*)(ws);
  unsigned short* kb = (unsigned short*)(ws + MB16);
  unsigned short* vT = (unsigned short*)(ws + 2 * MB16);
  float* rq = (float*)(ws + 3 * MB16);
  float* rk = (float*)(ws + 3 * MB16 + 32768);
  char* scr = ws + 3 * MB16 + 65536;
  unsigned short* x1b = (unsigned short*)(scr);
  unsigned short* x2b = (unsigned short*)(scr + MB16);
  unsigned short* wqT = (unsigned short*)(scr + 2 * MB16);
  unsigned short* wkT = (unsigned short*)(scr + 2 * MB16 + 2097152);
  unsigned short* wvT = (unsigned short*)(scr + 2 * MB16 + 2 * 2097152);
  unsigned short* zb  = (unsigned short*)(scr);  // reused after projections

  cvt_f32_bf16<<<4096, 256, 0, stream>>>(x1, x1b);
  cvt_f32_bf16<<<4096, 256, 0, stream>>>(x2, x2b);
  cvt_w_T<<<dim3(32, 32, 3), 256, 0, stream>>>(WQ, WK, WV, wqT, wkT, wvT);

  // merged q+k projection: rows 0..8191 vs WQ, 8192..16383 vs WK; C = qb||kb
  gemm8<0, 4><<<dim3(4, 64, 1), 512, 0, stream>>>(
      x1b, wqT, wkT, 8192, qb, 1024, 1024, 1024, 1024, 0, 0, 0, nullptr, nullptr, 0);

  // vT[e, n] = sum_k WV[k,e] * x2[n,k]  (v transposed), BN=128 -> 256 blocks
  gemm8<0, 2><<<dim3(64, 4, 1), 512, 0, stream>>>(
      wvT, x2b, x2b, 1 << 30, vT, 1024, 1024, 1024, 8192, 0, 0, 0, nullptr, nullptr, 0);

  rownorm<<<16384, 256, 0, stream>>>(qb, kb, rq, rk);

  // cosine scores z[b] = (q k^T) * rq x rk -> bf16
  gemm8<1, 4><<<dim3(8, 8, 4), 512, 0, stream>>>(
      qb, kb, kb, 1 << 30, zb, 1024, 1024, 1024, 2048,
      2048LL * 1024, 2048LL * 1024, 2048LL * 2048, rq, rk, 2048);

  softmax_rows<<<8192, 256, 0, stream>>>(zb);

  // y[b] = w[b] @ v[b] via BT-gemm against vT, BN=128 -> 256 blocks, fp32 out
  gemm8<2, 2><<<dim3(8, 8, 4), 512, 0, stream>>>(
      zb, vT, vT, 1 << 30, out, 2048, 2048, 8192, 1024,
      2048LL * 2048, 2048, 2048LL * 1024, nullptr, nullptr, 0);
}

// Round 4
// 286.713 us; speedup vs baseline: 1.2181x; 1.0352x over previous
//
#include <hip/hip_runtime.h>

// ContentBasedAttention: y = softmax(cos_sim(x1@WQ, x2@WK)) @ (x2@WV)
// B=4, S=2048, D=1024. fp32 in/out; internal bf16 MFMA.
// GEMM engine: BK=32, 4 LDS buffers, 3-tile prefetch lookahead, counted vmcnt
// (steady 8/6, never 0 mid-loop), paired-row XOR-swizzled LDS (conflict-free),
// global_load_lds staging with pre-swizzled per-thread source (rule 21).
// Two shapes, both 256 blocks: 256x256 (2 phases/tile) and 128x256 TALL (1 phase).

typedef __attribute__((ext_vector_type(4))) float f32x4;
typedef __attribute__((ext_vector_type(4))) unsigned short u16x4;
typedef __attribute__((ext_vector_type(8))) unsigned short u16x8;
typedef __attribute__((ext_vector_type(8))) __bf16 bf16x8;

__device__ __forceinline__ unsigned short f2b(float f) {
  unsigned u = __float_as_uint(f);
  u += 0x7FFFu + ((u >> 16) & 1u);
  return (unsigned short)(u >> 16);
}
__device__ __forceinline__ float b2f(unsigned short h) {
  return __uint_as_float(((unsigned)h) << 16);
}

__device__ __forceinline__ void gl_lds16(const void* g, void* l) {
  __builtin_amdgcn_global_load_lds(
      (const __attribute__((address_space(1))) void*)g,
      (__attribute__((address_space(3))) void*)l, 16, 0, 0);
}

// ---------------- elementwise converts ----------------

__global__ void cvt_f32_bf16(const float* __restrict__ in, unsigned short* __restrict__ out) {
  long long i = (long long)(blockIdx.x * 256 + threadIdx.x) * 8;
  f32x4 a = *(const f32x4*)(in + i);
  f32x4 b = *(const f32x4*)(in + i + 4);
  u16x8 o;
  o[0] = f2b(a[0]); o[1] = f2b(a[1]); o[2] = f2b(a[2]); o[3] = f2b(a[3]);
  o[4] = f2b(b[0]); o[5] = f2b(b[1]); o[6] = f2b(b[2]); o[7] = f2b(b[3]);
  *(u16x8*)(out + i) = o;
}

__global__ void cvt_w_T(const float* __restrict__ w0, const float* __restrict__ w1,
                        const float* __restrict__ w2,
                        unsigned short* __restrict__ o0, unsigned short* __restrict__ o1,
                        unsigned short* __restrict__ o2) {
  const float* src = blockIdx.z == 0 ? w0 : (blockIdx.z == 1 ? w1 : w2);
  unsigned short* dst = blockIdx.z == 0 ? o0 : (blockIdx.z == 1 ? o1 : o2);
  __shared__ float tile[32][33];
  const int t = threadIdx.x;
  const int r = t >> 3, c4 = (t & 7) << 2;
  f32x4 v = *(const f32x4*)(src + (long long)(blockIdx.y * 32 + r) * 1024 + blockIdx.x * 32 + c4);
  tile[r][c4 + 0] = v[0]; tile[r][c4 + 1] = v[1];
  tile[r][c4 + 2] = v[2]; tile[r][c4 + 3] = v[3];
  __syncthreads();
  u16x4 ov;
  ov[0] = f2b(tile[c4 + 0][r]); ov[1] = f2b(tile[c4 + 1][r]);
  ov[2] = f2b(tile[c4 + 2][r]); ov[3] = f2b(tile[c4 + 3][r]);
  *(u16x4*)(dst + (long long)(blockIdx.x * 32 + r) * 1024 + blockIdx.y * 32 + c4) = ov;
}

// ---------------- per-row rsqrt(sum sq) ----------------

__global__ void rownorm(const unsigned short* __restrict__ qb, const unsigned short* __restrict__ kb,
                        float* __restrict__ rq, float* __restrict__ rk) {
  const int row = blockIdx.x;
  const unsigned short* src;
  float* dst;
  if (row < 8192) { src = qb + (long long)row * 1024; dst = rq + row; }
  else            { src = kb + (long long)(row - 8192) * 1024; dst = rk + (row - 8192); }
  const int t = threadIdx.x;
  u16x4 v = *(const u16x4*)(src + t * 4);
  float s = 0.f;
#pragma unroll
  for (int i = 0; i < 4; ++i) { float f = b2f(v[i]); s += f * f; }
#pragma unroll
  for (int o = 32; o; o >>= 1) s += __shfl_xor(s, o);
  __shared__ float red[4];
  if ((t & 63) == 0) red[t >> 6] = s;
  __syncthreads();
  if (t == 0) {
    float tot = red[0] + red[1] + red[2] + red[3];
    *dst = rsqrtf(fmaxf(tot, 1e-12f));
  }
}

// ---------------- in-place row softmax over bf16 [*, 2048] ----------------

__global__ void softmax_rows(unsigned short* __restrict__ zb) {
  unsigned short* zr = zb + (long long)blockIdx.x * 2048;
  const int t = threadIdx.x;
  u16x8 v = *(const u16x8*)(zr + t * 8);
  float f[8];
#pragma unroll
  for (int i = 0; i < 8; ++i) f[i] = b2f(v[i]);
  float mx = f[0];
#pragma unroll
  for (int i = 1; i < 8; ++i) mx = fmaxf(mx, f[i]);
#pragma unroll
  for (int o = 32; o; o >>= 1) mx = fmaxf(mx, __shfl_xor(mx, o));
  __shared__ float red[4];
  if ((t & 63) == 0) red[t >> 6] = mx;
  __syncthreads();
  mx = fmaxf(fmaxf(red[0], red[1]), fmaxf(red[2], red[3]));
  float s = 0.f;
#pragma unroll
  for (int i = 0; i < 8; ++i) { f[i] = __expf(f[i] - mx); s += f[i]; }
  __syncthreads();
#pragma unroll
  for (int o = 32; o; o >>= 1) s += __shfl_xor(s, o);
  if ((t & 63) == 0) red[t >> 6] = s;
  __syncthreads();
  s = red[0] + red[1] + red[2] + red[3];
  float inv = 1.0f / s;
  u16x8 o8;
#pragma unroll
  for (int i = 0; i < 8; ++i) o8[i] = f2b(f[i] * inv);
  *(u16x8*)(zr + t * 8) = o8;
}

// ---------------- GEMM_BT engine ----------------
// C[m,n] = sum_k A[m,k]*B[n,k], A/B row-major bf16.
// BM = TALL?128:256, BN=256, BK=32. 512 threads = 8 waves (2M x 4N).
// LDS region per (buf, mat): rows paired 2-per-128B-LDS-row, 8 slots of 16B,
// logical (row g=2R+a, colquad q) stored at slot s=(4a+q)^(R&7):
//   read: 16-lane fragment hits each slot exactly twice -> 2/bank = free.
//   stage: thread t loads global row 2*(t>>3)+a_t, colquad q_t with
//   (4a_t+q_t) = (t&7)^((t>>3)&7) -> linear global_load_lds dest (rule 21).
// Pipeline: 4 buffers, tile kt stages tile kt+3 (A at p0, B at p1/TALL same
// phase). Steady wait at tile end: vmcnt(8) NF4 / vmcnt(6) TALL (= 2 tiles in
// flight); tails 4/3 then 0. Never drains mid-loop (T4).
// MODE 0: bf16 C. MODE 1: bf16 of acc*rowS[m]*colS[n]. MODE 2: fp32 C.

template <int MODE, int TALL>
__global__ __launch_bounds__(512, 2) void gemmk(
    const unsigned short* __restrict__ A,
    const unsigned short* __restrict__ B0_, const unsigned short* __restrict__ B1_, int bSplit,
    void* __restrict__ C, int K, int lda, int ldb, int ldc,
    long long strideA, long long strideB, long long strideC,
    const float* __restrict__ rowS, const float* __restrict__ colS, int scaleStride) {
  constexpr int BM = TALL ? 128 : 256;
  constexpr int AE = BM * 32;           // elems per A region
  constexpr int BE = 256 * 32;          // elems per B region
  constexpr int MF = TALL ? 4 : 8;      // m-fragments per wave
  __shared__ __align__(128) unsigned short sA[4][AE];
  __shared__ __align__(128) unsigned short sB[4][BE];

  // bijective XCD swizzle (nwg = 256, %8 == 0)
  const int gx = gridDim.x, gy = gridDim.y;
  int flat = blockIdx.x + gx * (blockIdx.y + gy * blockIdx.z);
  const int cpx = (gx * gy * gridDim.z) >> 3;
  flat = (flat & 7) * cpx + (flat >> 3);
  const int bx = flat % gx;
  const int rem = flat / gx;
  const int by = rem % gy;
  const int bz = rem / gy;

  const int bm0 = by * BM, bn0 = bx << 8;
  const unsigned short* Ab = A + (long long)bz * strideA;
  const unsigned short* Bb = ((bm0 < bSplit) ? B0_ : B1_) + (long long)bz * strideB;

  const int t = threadIdx.x, l = t & 63, w = t >> 6;
  const int wr = w >> 2, wc = w & 3;    // 2M x 4N waves
  const int fr = l & 15, fq = l >> 4;
  const long long ldaL = lda, ldbL = ldb;

  // per-lane read offset (elems) within a region: row g=fb+fr, colquad fq
  const int R0 = fr >> 1;
  const int lofs = R0 * 64 + ((((fr & 1) << 2) | fq) ^ R0) * 8;

  // per-thread staging source: LDS chunk t -> (R=t>>3, s=t&7)
  const int aq = (t & 7) ^ ((t >> 3) & 7);
  const int g0 = ((t >> 3) << 1) + (aq >> 2);
  const int q8 = (aq & 3) << 3;
  const unsigned short* gA_t = Ab + (long long)(bm0 + g0) * ldaL + q8;
  const unsigned short* gB_t = Bb + (long long)(bn0 + g0) * ldbL + q8;

  auto SA = [&](int kc, int buf) {
    gl_lds16(gA_t + kc, &sA[buf][t * 8]);
    if constexpr (!TALL) gl_lds16(gA_t + (long long)128 * ldaL + kc, &sA[buf][t * 8 + 4096]);
  };
  auto SB = [&](int kc, int buf) {
    gl_lds16(gB_t + kc, &sB[buf][t * 8]);
    gl_lds16(gB_t + (long long)128 * ldbL + kc, &sB[buf][t * 8 + 4096]);
  };

  f32x4 acc[MF][4] = {};
  const int NKT = K >> 5;

  // prologue: stage tiles 0,1,2; need tile 0 landed
#pragma unroll
  for (int j = 0; j < 3; ++j) { SA(j * 32, j); SB(j * 32, j); }
  if constexpr (!TALL) asm volatile("s_waitcnt vmcnt(8)" ::: "memory");
  else                 asm volatile("s_waitcnt vmcnt(6)" ::: "memory");
  __builtin_amdgcn_s_barrier();

  for (int kt = 0; kt < NKT; ++kt) {
    const unsigned short* aR = &sA[kt & 3][0];
    const unsigned short* bR = &sB[kt & 3][0];
    const int kc3 = (kt + 3) << 5;
    const int sb3 = (kt + 3) & 3;
    const bool st = (kt + 3 < NKT);
    bf16x8 bfr[4], af[4];

#pragma unroll
    for (int n = 0; n < 4; ++n)
      bfr[n] = *(const bf16x8*)(bR + (wc * 64 + n * 16) * 32 + lofs);
#pragma unroll
    for (int m = 0; m < 4; ++m)
      af[m] = *(const bf16x8*)(aR + (wr * (TALL ? 64 : 128) + m * 16) * 32 + lofs);
    if (st) SA(kc3, sb3);

    if constexpr (!TALL) {
      __builtin_amdgcn_s_setprio(1);
#pragma unroll
      for (int m = 0; m < 4; ++m)
#pragma unroll
        for (int n = 0; n < 4; ++n)
          acc[m][n] = __builtin_amdgcn_mfma_f32_16x16x32_bf16(af[m], bfr[n], acc[m][n], 0, 0, 0);
      __builtin_amdgcn_s_setprio(0);
      __builtin_amdgcn_s_barrier();   // end p0
      // p1: rows +64
#pragma unroll
      for (int m = 0; m < 4; ++m)
        af[m] = *(const bf16x8*)(aR + (wr * 128 + 64 + m * 16) * 32 + lofs);
      if (st) SB(kc3, sb3);
      __builtin_amdgcn_s_setprio(1);
#pragma unroll
      for (int m = 0; m < 4; ++m)
#pragma unroll
        for (int n = 0; n < 4; ++n)
          acc[4 + m][n] = __builtin_amdgcn_mfma_f32_16x16x32_bf16(af[m], bfr[n], acc[4 + m][n], 0, 0, 0);
      __builtin_amdgcn_s_setprio(0);
    } else {
      if (st) SB(kc3, sb3);
      __builtin_amdgcn_s_setprio(1);
#pragma unroll
      for (int m = 0; m < 4; ++m)
#pragma unroll
        for (int n = 0; n < 4; ++n)
          acc[m][n] = __builtin_amdgcn_mfma_f32_16x16x32_bf16(af[m], bfr[n], acc[m][n], 0, 0, 0);
      __builtin_amdgcn_s_setprio(0);
    }

    // tile-end counted wait: next tile must be landed before its reads
    if (kt + 3 < NKT) {
      if constexpr (!TALL) asm volatile("s_waitcnt vmcnt(8)" ::: "memory");
      else                 asm volatile("s_waitcnt vmcnt(6)" ::: "memory");
    } else if (kt + 3 == NKT) {
      if constexpr (!TALL) asm volatile("s_waitcnt vmcnt(4)" ::: "memory");
      else                 asm volatile("s_waitcnt vmcnt(3)" ::: "memory");
    } else if (kt + 2 == NKT) {
      asm volatile("s_waitcnt vmcnt(0)" ::: "memory");
    }
    __builtin_amdgcn_s_barrier();
  }

  // epilogue: acc[am][n][jj] -> row bm0 + wr*(TALL?64:128) + (am>>2)*64 + (am&3)*16 + fq*4 + jj
  //           col bn0 + wc*64 + n*16 + fr
  const int rbase = bm0 + wr * (TALL ? 64 : 128) + fq * 4;
  const int c0 = bn0 + wc * 64 + fr;
  if constexpr (MODE == 0) {
    unsigned short* Cp = (unsigned short*)C + (long long)bz * strideC;
#pragma unroll
    for (int m = 0; m < MF; ++m)
#pragma unroll
      for (int jj = 0; jj < 4; ++jj) {
        const int rr = rbase + (m >> 2) * 64 + (m & 3) * 16 + jj;
        const long long rb = (long long)rr * ldc + c0;
#pragma unroll
        for (int n = 0; n < 4; ++n) Cp[rb + n * 16] = f2b(acc[m][n][jj]);
      }
  } else if constexpr (MODE == 1) {
    unsigned short* Cp = (unsigned short*)C + (long long)bz * strideC;
    const float* rs = rowS + bz * scaleStride;
    const float* cs = colS + bz * scaleStride;
    float csv[4];
#pragma unroll
    for (int n = 0; n < 4; ++n) csv[n] = cs[c0 + n * 16];
#pragma unroll
    for (int m = 0; m < MF; ++m)
#pragma unroll
      for (int jj = 0; jj < 4; ++jj) {
        const int rr = rbase + (m >> 2) * 64 + (m & 3) * 16 + jj;
        const float rsv = rs[rr];
        const long long rb = (long long)rr * ldc + c0;
#pragma unroll
        for (int n = 0; n < 4; ++n) Cp[rb + n * 16] = f2b(acc[m][n][jj] * rsv * csv[n]);
      }
  } else {
    float* Cp = (float*)C + (long long)bz * strideC;
#pragma unroll
    for (int m = 0; m < MF; ++m)
#pragma unroll
      for (int jj = 0; jj < 4; ++jj) {
        const int rr = rbase + (m >> 2) * 64 + (m & 3) * 16 + jj;
        const long long rb = (long long)rr * ldc + c0;
#pragma unroll
        for (int n = 0; n < 4; ++n) Cp[rb + n * 16] = acc[m][n][jj];
      }
  }
}

// ---------------- launch ----------------

extern "C" void kernel_launch(void* const* d_in, const int* in_sizes, int n_in,
                              void* d_out, int out_size, void* d_ws, size_t ws_size,
                              hipStream_t stream) {
  (void)in_sizes; (void)n_in; (void)out_size; (void)ws_size;
  const float* x1 = (const float*)d_in[0];
  const float* x2 = (const float*)d_in[1];
  const float* WQ = (const float*)d_in[2];
  const float* WK = (const float*)d_in[3];
  const float* WV = (const float*)d_in[4];
  float* out = (float*)d_out;
  char* ws = (char*)d_ws;

  const long long MB16 = 16777216LL;
  unsigned short* qb = (unsigned short*)(ws);
  unsigned short* kb = (unsigned short*)(ws + MB16);
  unsigned short* vT = (unsigned short*)(ws + 2 * MB16);
  float* rq = (float*)(ws + 3 * MB16);
  float* rk = (float*)(ws + 3 * MB16 + 32768);
  char* scr = ws + 3 * MB16 + 65536;
  unsigned short* x1b = (unsigned short*)(scr);
  unsigned short* x2b = (unsigned short*)(scr + MB16);
  unsigned short* wqT = (unsigned short*)(scr + 2 * MB16);
  unsigned short* wkT = (unsigned short*)(scr + 2 * MB16 + 2097152);
  unsigned short* wvT = (unsigned short*)(scr + 2 * MB16 + 2 * 2097152);
  unsigned short* zb  = (unsigned short*)(scr);  // reused after projections

  cvt_f32_bf16<<<4096, 256, 0, stream>>>(x1, x1b);
  cvt_f32_bf16<<<4096, 256, 0, stream>>>(x2, x2b);
  cvt_w_T<<<dim3(32, 32, 3), 256, 0, stream>>>(WQ, WK, WV, wqT, wkT, wvT);

  // merged q+k projection: rows 0..8191 vs WQ, 8192..16383 vs WK; C = qb||kb
  gemmk<0, 0><<<dim3(4, 64, 1), 512, 0, stream>>>(
      x1b, wqT, wkT, 8192, qb, 1024, 1024, 1024, 1024, 0, 0, 0, nullptr, nullptr, 0);

  // vT[e, n] = sum_k WV[k,e] * x2[n,k] (v transposed), TALL 128x256: grid (32,8)=256
  gemmk<0, 1><<<dim3(32, 8, 1), 512, 0, stream>>>(
      wvT, x2b, x2b, 1 << 30, vT, 1024, 1024, 1024, 8192, 0, 0, 0, nullptr, nullptr, 0);

  rownorm<<<16384, 256, 0, stream>>>(qb, kb, rq, rk);

  // cosine scores z[b] = (q k^T) * rq x rk -> bf16, 256x256: grid (8,8,4)=256
  gemmk<1, 0><<<dim3(8, 8, 4), 512, 0, stream>>>(
      qb, kb, kb, 1 << 30, zb, 1024, 1024, 1024, 2048,
      2048LL * 1024, 2048LL * 1024, 2048LL * 2048, rq, rk, 2048);

  softmax_rows<<<8192, 256, 0, stream>>>(zb);

  // y[b] = w[b] @ v[b] via BT-gemm vs vT, TALL 128x256: grid (4,16,4)=256, fp32 out
  gemmk<2, 1><<<dim3(4, 16, 4), 512, 0, stream>>>(
      zb, vT, vT, 1 << 30, out, 2048, 2048, 8192, 1024,
      2048LL * 2048, 2048, 2048LL * 1024, nullptr, nullptr, 0);
}